// Round 4
// baseline (42.091 us; speedup 1.0000x reference)
//
#include <hip/hip_runtime.h>
#include <math.h>

// v3: Fused MLP, bf16 MFMA, barrier-minimized.
//  - prepass kernel: weights fp32 -> bf16 into d_ws (w1 padded [128][896],
//    w2 [256][128], w3 padded [16][256]); main kernel stages weights with
//    global_load_lds width=16, source pre-XOR-swizzled (LDS stays linear).
//  - x (the big stream) never goes through LDS: A-fragments loaded
//    global->reg per wave (each wave owns its 16 batch rows), cvt in reg.
//  - Layer1: K-tiles of 128, w1 tile double-buffered (2x32KB) -> 1 barrier/tile,
//    glds for kt+1 in flight under kt's MFMAs. 7 tiles.
//  - Layer2: stage all of w2 (64KB) once. Layer3: h2+w3 overlay w-region.
//  - All LDS reads XOR-swizzled (phys_slot = slot ^ (row&7)) -> b128 floor.
// 512 thr (8 waves: mi=wv&3 M-tile, nh=wv>>2 N-half), 512 blocks, 80KB LDS.

#define TPB 512
#define BROWS 64

// ws layout in shorts (bf16):
#define W2OFF 114688   // w1b [128][896] @ 0   (zeros for k>=784)
#define W3OFF 147456   // w2b [256][128] @ W2OFF
#define WTOT  151552   // w3b [16][256]  @ W3OFF (zeros rows >=10)

typedef __attribute__((ext_vector_type(8))) short bf16x8;
typedef __attribute__((ext_vector_type(4))) float f32x4;

static __device__ inline short f2bf(float f) {
    union { float f; unsigned u; } v; v.f = f;
    unsigned r = v.u + 0x7fffu + ((v.u >> 16) & 1u);   // RNE
    return (short)(r >> 16);
}
static __device__ inline bf16x8 cvt8(float4 a, float4 b) {
    bf16x8 r;
    r[0]=f2bf(a.x); r[1]=f2bf(a.y); r[2]=f2bf(a.z); r[3]=f2bf(a.w);
    r[4]=f2bf(b.x); r[5]=f2bf(b.y); r[6]=f2bf(b.z); r[7]=f2bf(b.w);
    return r;
}
static __device__ inline float4 ld4g(const float* p, bool ok) {
    return ok ? *reinterpret_cast<const float4*>(p) : make_float4(0.f,0.f,0.f,0.f);
}
static __device__ inline void gld16(const short* g, short* l) {
    __builtin_amdgcn_global_load_lds(
        (const __attribute__((address_space(1))) unsigned int*)g,
        (__attribute__((address_space(3))) unsigned int*)l, 16, 0, 0);
}

__global__ void prep_weights(const float* __restrict__ w1,
                             const float* __restrict__ w2,
                             const float* __restrict__ w3,
                             short* __restrict__ wb) {
    const int idx = blockIdx.x * blockDim.x + threadIdx.x;
    if (idx >= WTOT) return;
    short v;
    if (idx < W2OFF) {
        const int r = idx / 896, k = idx - r * 896;
        v = (k < 784) ? f2bf(w1[r * 784 + k]) : (short)0;
    } else if (idx < W3OFF) {
        v = f2bf(w2[idx - W2OFF]);
    } else {
        const int j = idx - W3OFF;
        const int r = j >> 8, k = j & 255;
        v = (r < 10) ? f2bf(w3[r * 256 + k]) : (short)0;
    }
    wb[idx] = v;
}

__global__ __launch_bounds__(TPB, 4) void mnist_v3(
    const float* __restrict__ x,    // [32768,784]
    const float* __restrict__ b1v,  // [128]
    const float* __restrict__ b2v,  // [256]
    const float* __restrict__ b3v,  // [10]
    const short* __restrict__ wb,   // bf16 weights (prepass)
    float* __restrict__ out)        // [32768,10]
{
    __shared__ __align__(16) short s_w[2][16384];  // 64KB: w1 dbuf / w2 full / {h2,w3}
    __shared__ __align__(16) short s_h1[64 * 128]; // 16KB
    short* const s_wf = &s_w[0][0];
    short* const s_h2 = &s_w[0][0];                // [64][256] overlay
    short* const s_w3 = &s_w[1][0];                // [16][256] overlay

    const int t    = threadIdx.x;
    const int lane = t & 63;
    const int wv   = t >> 6;
    const int mi   = wv & 3;          // M-tile: rows 16*mi..+15
    const int nh   = wv >> 2;         // N-half
    const int l15  = lane & 15;
    const int l4   = lane >> 4;
    const int row0 = blockIdx.x * BROWS;
    const int lr4  = lane >> 4;       // row-within-chunk (16-slot rows)
    const int ls16 = lane & 15;       // phys slot (16-slot rows)

    // ---------------- Layer 1: [64,784] x [784,128], 7 K-tiles of 128 ----------
    f32x4 acc1[4];
    #pragma unroll
    for (int f = 0; f < 4; ++f) acc1[f] = (f32x4){0.f,0.f,0.f,0.f};

    // prologue: stage w1 tile 0 -> buf 0
    #pragma unroll
    for (int p = 0; p < 4; ++p) {
        const int chunk = wv * 4 + p;
        const int row   = chunk * 4 + lr4;
        const int src   = row * 896 + ((ls16 ^ (row & 7)) << 3);
        gld16(&wb[src], &s_w[0][chunk * 512]);
    }
    __syncthreads();

    const float* xrow = &x[(size_t)(row0 + 16 * mi + l15) * 784];
    for (int kt = 0; kt < 7; ++kt) {
        const int cur = kt & 1;
        const int k0  = kt * 128;
        // A: direct global->reg (issued first so their consumption doesn't drain glds)
        float4 xa[4], xb[4];
        #pragma unroll
        for (int kk = 0; kk < 4; ++kk) {
            const int kg = k0 + kk * 32 + l4 * 8;
            const bool ok = (kg + 8) <= 784;
            xa[kk] = ld4g(xrow + kg, ok);
            xb[kk] = ld4g(xrow + kg + 4, ok);
        }
        // prefetch w1 tile kt+1 into other buf (in flight under MFMAs)
        if (kt < 6) {
            #pragma unroll
            for (int p = 0; p < 4; ++p) {
                const int chunk = wv * 4 + p;
                const int row   = chunk * 4 + lr4;
                const int src   = row * 896 + (kt + 1) * 128 + ((ls16 ^ (row & 7)) << 3);
                gld16(&wb[src], &s_w[cur ^ 1][chunk * 512]);
            }
        }
        bf16x8 a[4];
        #pragma unroll
        for (int kk = 0; kk < 4; ++kk) a[kk] = cvt8(xa[kk], xb[kk]);
        #pragma unroll
        for (int f = 0; f < 4; ++f) {
            const int rB = nh * 64 + f * 16 + l15;
            #pragma unroll
            for (int kk = 0; kk < 4; ++kk) {
                const bf16x8 b = *reinterpret_cast<const bf16x8*>(
                    &s_w[cur][rB * 128 + (((kk * 4 + l4) ^ (l15 & 7)) << 3)]);
                acc1[f] = __builtin_amdgcn_mfma_f32_16x16x32_bf16(a[kk], b, acc1[f], 0, 0, 0);
            }
        }
        __syncthreads();   // all waves done with buf cur; next iter's glds may overwrite it
    }

    // stage all of w2 [256][128] -> s_wf (64KB); latency hidden under h1 epilogue
    #pragma unroll
    for (int p = 0; p < 8; ++p) {
        const int chunk = wv * 8 + p;
        const int row   = chunk * 4 + lr4;
        const int src   = W2OFF + row * 128 + ((ls16 ^ (row & 7)) << 3);
        gld16(&wb[src], &s_wf[chunk * 512]);
    }
    // h1 epilogue: bias+relu -> s_h1 [64][128] swizzled
    #pragma unroll
    for (int f = 0; f < 4; ++f) {
        const int c  = nh * 64 + f * 16 + l15;
        const float bc = b1v[c];
        #pragma unroll
        for (int i = 0; i < 4; ++i) {
            const int r = 16 * mi + l4 * 4 + i;
            float h = acc1[f][i] + bc;
            h = h > 0.f ? h : 0.f;
            s_h1[r * 128 + (((c >> 3) ^ (r & 7)) << 3) + (c & 7)] = f2bf(h);
        }
    }
    __syncthreads();

    // ---------------- Layer 2: [64,128] x [128,256], single shot ---------------
    f32x4 acc2[8];
    #pragma unroll
    for (int f = 0; f < 8; ++f) acc2[f] = (f32x4){0.f,0.f,0.f,0.f};
    bf16x8 a2[4];
    #pragma unroll
    for (int kk = 0; kk < 4; ++kk)
        a2[kk] = *reinterpret_cast<const bf16x8*>(
            &s_h1[(16 * mi + l15) * 128 + (((kk * 4 + l4) ^ (l15 & 7)) << 3)]);
    #pragma unroll
    for (int f = 0; f < 8; ++f) {
        const int rB = nh * 128 + f * 16 + l15;
        #pragma unroll
        for (int kk = 0; kk < 4; ++kk) {
            const bf16x8 b = *reinterpret_cast<const bf16x8*>(
                &s_wf[rB * 128 + (((kk * 4 + l4) ^ (l15 & 7)) << 3)]);
            acc2[f] = __builtin_amdgcn_mfma_f32_16x16x32_bf16(a2[kk], b, acc2[f], 0, 0, 0);
        }
    }
    __syncthreads();   // all waves done reading s_wf/s_h1 before overlaying

    // stage w3 [16][256] -> s_w3 (8KB)
    {
        const int row = wv * 2 + (lane >> 5);
        const int sp  = lane & 31;
        const int src = W3OFF + row * 256 + ((sp ^ (row & 7)) << 3);
        gld16(&wb[src], &s_w3[wv * 512]);
    }
    // h2 epilogue: bias+relu -> s_h2 [64][256] swizzled (overlay on s_w[0])
    #pragma unroll
    for (int f = 0; f < 8; ++f) {
        const int c  = nh * 128 + f * 16 + l15;
        const float bc = b2v[c];
        #pragma unroll
        for (int i = 0; i < 4; ++i) {
            const int r = 16 * mi + l4 * 4 + i;
            float h = acc2[f][i] + bc;
            h = h > 0.f ? h : 0.f;
            s_h2[r * 256 + (((c >> 3) ^ (r & 7)) << 3) + (c & 7)] = f2bf(h);
        }
    }
    __syncthreads();

    // ---------------- Layer 3 (nh==0 waves) + log_softmax ----------------------
    if (nh == 0) {
        f32x4 acc3 = (f32x4){0.f,0.f,0.f,0.f};
        #pragma unroll
        for (int kt = 0; kt < 8; ++kt) {
            const int slot = kt * 4 + l4;
            const bf16x8 a = *reinterpret_cast<const bf16x8*>(
                &s_h2[(16 * mi + l15) * 256 + ((slot ^ (l15 & 7)) << 3)]);
            const bf16x8 b = *reinterpret_cast<const bf16x8*>(
                &s_w3[l15 * 256 + ((slot ^ (l15 & 7)) << 3)]);
            acc3 = __builtin_amdgcn_mfma_f32_16x16x32_bf16(a, b, acc3, 0, 0, 0);
        }
        const float b3c = (l15 < 10) ? b3v[l15] : 0.f;
        #pragma unroll
        for (int i = 0; i < 4; ++i) {
            const float v = acc3[i] + b3c;
            float m = (l15 < 10) ? v : -1e30f;
            #pragma unroll
            for (int off = 8; off; off >>= 1) m = fmaxf(m, __shfl_xor(m, off, 16));
            const float e = (l15 < 10) ? expf(v - m) : 0.f;
            float sum = e;
            #pragma unroll
            for (int off = 8; off; off >>= 1) sum += __shfl_xor(sum, off, 16);
            const float ls = m + logf(sum);
            if (l15 < 10) {
                const int r = row0 + 16 * mi + l4 * 4 + i;
                out[(size_t)r * 10 + l15] = v - ls;
            }
        }
    }
}

extern "C" void kernel_launch(void* const* d_in, const int* in_sizes, int n_in,
                              void* d_out, int out_size, void* d_ws, size_t ws_size,
                              hipStream_t stream) {
    const float* x  = (const float*)d_in[0];
    const float* w1 = (const float*)d_in[1];
    const float* b1 = (const float*)d_in[2];
    const float* w2 = (const float*)d_in[3];
    const float* b2 = (const float*)d_in[4];
    const float* w3 = (const float*)d_in[5];
    const float* b3 = (const float*)d_in[6];
    float* out = (float*)d_out;
    short* wb  = (short*)d_ws;   // needs WTOT*2 = ~303KB of scratch

    prep_weights<<<(WTOT + TPB - 1) / TPB, TPB, 0, stream>>>(w1, w2, w3, wb);

    const int B = 32768;
    dim3 grid(B / BROWS), block(TPB);
    mnist_v3<<<grid, block, 0, stream>>>(x, b1, b2, b3, wb, out);
}